// Round 4
// baseline (362.258 us; speedup 1.0000x reference)
//
#include <hip/hip_runtime.h>

// Problem constants (B,T,C,H fixed by the reference).
constexpr int Bn = 4, Tn = 2048, Cn = 1024, Hn = 16, Dn = 64;

typedef __attribute__((ext_vector_type(8))) short short8;
typedef __attribute__((ext_vector_type(4))) float floatx4;
typedef __attribute__((ext_vector_type(2))) unsigned uint2v;

#define DEVFN __device__ __forceinline__

// exp(s/8) = exp2(s * log2e/8); folded into Q at GEMM1 epilogue.
constexpr float SCL = 0.18033688011112042f;

// RTNE float -> bf16 raw bits (inputs are finite; no NaN handling needed).
DEVFN unsigned f2bf_u(float f) {
  unsigned u = __builtin_bit_cast(unsigned, f);
  u += 0x7fffu + ((u >> 16) & 1u);
  return u >> 16;
}
DEVFN short f2bf(float f) { return (short)f2bf_u(f); }

DEVFN floatx4 mfma16(short8 a, short8 b, floatx4 c) {
  return __builtin_amdgcn_mfma_f32_16x16x32_bf16(a, b, c, 0, 0, 0);
}

// Async global->LDS, 16B/lane. LDS dest must be wave-uniform base + lane*16.
DEVFN void gld_lds16(const void* g, void* l) {
  __builtin_amdgcn_global_load_lds(
      (const __attribute__((address_space(1))) unsigned*)g,
      (__attribute__((address_space(3))) unsigned*)l, 16, 0, 0);
}

// ---------------------------------------------------------------- cast fp32->bf16
__global__ __launch_bounds__(256) void cast_bf16_kernel(
    const float* __restrict__ in, short* __restrict__ out, int n8) {
  int i = blockIdx.x * 256 + threadIdx.x;
  if (i >= n8) return;
  const floatx4* p = (const floatx4*)in + (size_t)i * 2;
  floatx4 a = p[0], b = p[1];
  short8 r;
  r[0] = f2bf(a[0]); r[1] = f2bf(a[1]); r[2] = f2bf(a[2]); r[3] = f2bf(a[3]);
  r[4] = f2bf(b[0]); r[5] = f2bf(b[1]); r[6] = f2bf(b[2]); r[7] = f2bf(b[3]);
  ((short8*)out)[i] = r;
}

// ---------------------------------------------------------------- GEMM  Y = A @ B^T
// MODE 0: QKV projection. Q cols [0,1024) are PRE-SCALED by log2e/8 (softmax
//         fold). Q|K -> qkb [M,2048]; V cols [2048,3072) written transposed
//         into vtb[B][H][D][T] (b64-packed: consecutive acc regs = consecutive t).
// MODE 1: output projection: fp32 out + bias.
template <int MODE>
__global__ __launch_bounds__(256, 2) void gemm_bt(
    const short* __restrict__ A, const short* __restrict__ Bw, int M, int N, int K,
    short* __restrict__ qkb, short* __restrict__ vtb,
    const float* __restrict__ bias, float* __restrict__ fout) {
  __shared__ short As[128 * 32];
  __shared__ short Bs[128 * 32];
  const int tid = threadIdx.x;
  const int lane = tid & 63, wave = tid >> 6;
  const int l15 = lane & 15, quad = lane >> 4;
  const int wr = wave >> 1, wc = wave & 1;
  const int m0 = blockIdx.x * 128, n0 = blockIdx.y * 128;

  const int srow = tid >> 2;
  const int scol = (tid & 3) * 8;
  const short* Ag = A + (size_t)(m0 + srow) * K + scol;
  const short* Bg = Bw + (size_t)(n0 + srow) * K + scol;
  short* AsW = As + tid * 8;
  short* BsW = Bs + tid * 8;

  floatx4 acc[4][4] = {};

  for (int k0 = 0; k0 < K; k0 += 32) {
    gld_lds16(Ag + k0, AsW);
    gld_lds16(Ag + (size_t)64 * K + k0, AsW + 64 * 32);
    gld_lds16(Bg + k0, BsW);
    gld_lds16(Bg + (size_t)64 * K + k0, BsW + 64 * 32);
    __syncthreads();
    short8 af[4], bf[4];
#pragma unroll
    for (int i = 0; i < 4; ++i)
      af[i] = *(const short8*)(As + (wr * 64 + i * 16 + l15) * 32 + quad * 8);
#pragma unroll
    for (int i = 0; i < 4; ++i)
      bf[i] = *(const short8*)(Bs + (wc * 64 + i * 16 + l15) * 32 + quad * 8);
#pragma unroll
    for (int mi = 0; mi < 4; ++mi)
#pragma unroll
      for (int ni = 0; ni < 4; ++ni)
        acc[mi][ni] = mfma16(af[mi], bf[ni], acc[mi][ni]);
    __syncthreads();
  }

  // Epilogue. C/D layout: col = lane&15 (n), row = quad*4 + reg (m). [m89/m91]
#pragma unroll
  for (int mi = 0; mi < 4; ++mi) {
    const int row0 = m0 + wr * 64 + mi * 16 + quad * 4;
#pragma unroll
    for (int ni = 0; ni < 4; ++ni) {
      const int col = n0 + wc * 64 + ni * 16 + l15;
      if constexpr (MODE == 0) {
        if (col < 2 * Cn) {  // wave-uniform branch (128 | 2048 alignment)
#pragma unroll
          for (int r = 0; r < 4; ++r) {
            float v = acc[mi][ni][r];
            if (col < Cn) v *= SCL;  // softmax scale folded into Q
            qkb[(size_t)(row0 + r) * (2 * Cn) + col] = f2bf(v);
          }
        } else {
          const int hc = col - 2 * Cn;
          const int hh = hc >> 6, d = hc & 63;
          const int bb = row0 >> 11, t = row0 & (Tn - 1);
          uint2v pk;
          pk[0] = f2bf_u(acc[mi][ni][0]) | (f2bf_u(acc[mi][ni][1]) << 16);
          pk[1] = f2bf_u(acc[mi][ni][2]) | (f2bf_u(acc[mi][ni][3]) << 16);
          *(uint2v*)(vtb + ((size_t)((bb * Hn + hh) * Dn + d)) * Tn + t) = pk;
        }
      } else {
#pragma unroll
        for (int r = 0; r < 4; ++r)
          fout[(size_t)(row0 + r) * N + col] = acc[mi][ni][r] + bias[col];
      }
    }
  }
}

// ---------------------------------------------------------------- flash attention
// Block = 4 waves; wave owns 32 Q rows (2 i-frags). KV tile = 64, double-
// buffered LDS via async global_load_lds, ONE barrier per tile. XOR-swizzled
// LDS layouts (16B chunk ^= row&7) applied on the stager's GLOBAL address.
// Transposed math: S^T = K.Q^T, O^T = V^T.P^T; no online max; per-lane row
// sums reduced once at the end. P round-trip through per-wave 2KB LDS is done
// PER i-frag (halves Ps; LDS 40KB -> 4 blocks/CU at VGPR<=128).
// Flat grid with XCD swizzle: all 16 q-tiles of a bh land on one XCD (L2
// keeps that bh's K+V slices, ~4MB for its 8 bh).
__global__ __launch_bounds__(256, 4) void attn_kernel(
    const short* __restrict__ qk, const short* __restrict__ vt,
    short* __restrict__ att) {
  __shared__ short Ks[2][64 * 64];
  __shared__ short Vs[2][64 * 64];
  __shared__ short Ps[4][16 * 64];  // per-wave P-frag scratch (2 KB)

  const int id = blockIdx.x;           // 0..1023
  const int g = id & 7, sid = id >> 3; // XCD, slot
  const int bh = g * 8 + (sid >> 4);   // 8 bh per XCD
  const int qt = 15 - (sid & 15);      // longest blocks first
  const int b = bh >> 4, h = bh & 15;
  const int tid = threadIdx.x;
  const int lane = tid & 63, wave = tid >> 6;
  const int l15 = lane & 15, quad = lane >> 4;
  const int q0w = qt * 128 + wave * 32;  // this wave's 32 Q rows

  const short* qbase = qk + (size_t)(b * Tn) * 2048 + h * 64;
  const short* kbase = qbase + 1024;
  const short* vbase = vt + (size_t)(bh * 64) * Tn;
  short* pw = Ps[wave];

  // Q^T fragments (B-operand rows [i][c]) in registers for the whole kernel.
  short8 qf[2][2];
#pragma unroll
  for (int f = 0; f < 2; ++f)
#pragma unroll
    for (int ks = 0; ks < 2; ++ks)
      qf[f][ks] = *(const short8*)(qbase + (size_t)(q0w + f * 16 + l15) * 2048 +
                                   ks * 32 + quad * 8);

  floatx4 o[2][4] = {};         // O^T accumulator [f][nd], C-layout (row=d, col=i)
  float lpart[2] = {0.f, 0.f};  // per-lane row sums (i = l15)

  const int wave_nt = ((q0w + 31) >> 6) + 1;  // tiles this wave computes
  const int block_nt = 2 * qt + 2;            // loop count (uniform per block)

  const int jr = tid >> 3;  // staging row 0..31 (+32 on 2nd pass)
  const int cl = tid & 7;   // staging LDS chunk

#define STAGE(JT, BUF)                                                       \
  {                                                                          \
    const int j0s = (JT) * 64;                                               \
    _Pragma("unroll") for (int it = 0; it < 2; ++it) {                       \
      const int row = jr + it * 32;                                          \
      const int cg = cl ^ (row & 7);                                         \
      gld_lds16(kbase + (size_t)(j0s + row) * 2048 + cg * 8,                 \
                &Ks[BUF][it * 2048 + tid * 8]);                              \
      gld_lds16(vbase + (size_t)row * Tn + j0s + cg * 8,                     \
                &Vs[BUF][it * 2048 + tid * 8]);                              \
    }                                                                        \
  }

  STAGE(0, 0)
  __syncthreads();

  for (int jt = 0; jt < block_nt; ++jt) {
    const int buf = jt & 1;
    if (jt + 1 < block_nt) STAGE(jt + 1, buf ^ 1)

    if (jt < wave_nt) {
      const int j0 = jt * 64;

      // ---- S^T = K.Q^T for both i-frags; kf in 2 batches (VGPR cap 128)
      floatx4 st[2][4];
#pragma unroll
      for (int f = 0; f < 2; ++f)
#pragma unroll
        for (int nj = 0; nj < 4; ++nj) st[f][nj] = floatx4{0.f, 0.f, 0.f, 0.f};
#pragma unroll
      for (int half = 0; half < 2; ++half) {
        short8 kfa[2][2];
#pragma unroll
        for (int j2 = 0; j2 < 2; ++j2)
#pragma unroll
          for (int ks = 0; ks < 2; ++ks) {
            const int cld = (ks * 4 + quad) ^ (l15 & 7);
            kfa[j2][ks] = *(const short8*)(
                &Ks[buf][((half * 2 + j2) * 16 + l15) * 64 + cld * 8]);
          }
#pragma unroll
        for (int f = 0; f < 2; ++f)
#pragma unroll
          for (int j2 = 0; j2 < 2; ++j2)
#pragma unroll
            for (int ks = 0; ks < 2; ++ks)
              st[f][half * 2 + j2] =
                  mfma16(kfa[j2][ks], qf[f][ks], st[f][half * 2 + j2]);
      }

      // ---- V^T fragments (A-operand rows [d][j]), shared by both i-frags
      short8 vf[4][2];
#pragma unroll
      for (int nd = 0; nd < 4; ++nd)
#pragma unroll
        for (int ks = 0; ks < 2; ++ks) {
          const int cld = (ks * 4 + quad) ^ (l15 & 7);
          vf[nd][ks] =
              *(const short8*)(&Vs[buf][(nd * 16 + l15) * 64 + cld * 8]);
        }

      // ---- per i-frag: exp -> P -> LDS -> PV  (2KB per-wave scratch)
#pragma unroll
      for (int f = 0; f < 2; ++f) {
        const bool need_mask = (j0 + 63 > q0w + f * 16);
        const int ig = q0w + f * 16 + l15;
#pragma unroll
        for (int nj = 0; nj < 4; ++nj) {
          float p[4];
#pragma unroll
          for (int r = 0; r < 4; ++r) {
            float e = __builtin_amdgcn_exp2f(st[f][nj][r]);
            if (need_mask) {
              const int jg = j0 + nj * 16 + quad * 4 + r;
              e = (jg > ig) ? 0.f : e;
            }
            lpart[f] += e;
            p[r] = e;
          }
          // rows j = nj*16+quad*4 .. +3 are consecutive -> one b64 write
          const int c = nj * 2 + (quad >> 1);
          const int cld = c ^ (l15 & 7);
          uint2v pk;
          pk[0] = f2bf_u(p[0]) | (f2bf_u(p[1]) << 16);
          pk[1] = f2bf_u(p[2]) | (f2bf_u(p[3]) << 16);
          *(uint2v*)(&pw[l15 * 64 + cld * 8 + (quad & 1) * 4]) = pk;
        }
        // wave-local: drain P writes (lanes lockstep; DS ops in-order)
        __asm__ volatile("s_waitcnt lgkmcnt(0)" ::: "memory");

        short8 pf[2];
#pragma unroll
        for (int ks = 0; ks < 2; ++ks) {
          const int cld = (ks * 4 + quad) ^ (l15 & 7);
          pf[ks] = *(const short8*)(&pw[l15 * 64 + cld * 8]);
        }
#pragma unroll
        for (int nd = 0; nd < 4; ++nd)
#pragma unroll
          for (int ks = 0; ks < 2; ++ks)
            o[f][nd] = mfma16(vf[nd][ks], pf[ks], o[f][nd]);
        __asm__ volatile("" ::: "memory");  // keep f=1 P writes after pf reads
      }
    }
    __syncthreads();
  }

  // ---- final row sums: i = l15 -> only 2 cross-quad shuffles per frag
  float inv[2];
#pragma unroll
  for (int f = 0; f < 2; ++f) {
    float s2 = lpart[f];
    s2 += __shfl_xor(s2, 16);
    s2 += __shfl_xor(s2, 32);
    inv[f] = 1.0f / s2;
  }

  // ---- un-transpose O via per-wave LDS (16x64 per pass), coalesced stores
#pragma unroll
  for (int f = 0; f < 2; ++f) {
#pragma unroll
    for (int nd = 0; nd < 4; ++nd) {
      const int c = nd * 2 + (quad >> 1);
      const int cld = c ^ (l15 & 7);
      uint2v pk;
      pk[0] =
          f2bf_u(o[f][nd][0] * inv[f]) | (f2bf_u(o[f][nd][1] * inv[f]) << 16);
      pk[1] =
          f2bf_u(o[f][nd][2] * inv[f]) | (f2bf_u(o[f][nd][3] * inv[f]) << 16);
      *(uint2v*)(&pw[l15 * 64 + cld * 8 + (quad & 1) * 4]) = pk;
    }
    __asm__ volatile("s_waitcnt lgkmcnt(0)" ::: "memory");
#pragma unroll
    for (int ps = 0; ps < 2; ++ps) {
      const int r16 = ps * 8 + (lane >> 3);  // 0..15
      const int cn = lane & 7;
      const int cldr = cn ^ (r16 & 7);
      const short8 val = *(const short8*)(&pw[r16 * 64 + cldr * 8]);
      *(short8*)(att + (size_t)(b * Tn + q0w + f * 16 + r16) * Cn + h * 64 +
                 cn * 8) = val;
    }
    __asm__ volatile("" ::: "memory");  // f=1 writes stay after f=0 reads
  }
#undef STAGE
}

// ---------------------------------------------------------------- launch
extern "C" void kernel_launch(void* const* d_in, const int* in_sizes, int n_in,
                              void* d_out, int out_size, void* d_ws,
                              size_t ws_size, hipStream_t stream) {
  const float* x = (const float*)d_in[0];      // [B,T,C]
  const float* w_qkv = (const float*)d_in[1];  // [3C,C]
  const float* w_out = (const float*)d_in[2];  // [C,C]
  const float* b_out = (const float*)d_in[3];  // [C]
  float* out = (float*)d_out;                  // [B,T,C] fp32

  // Workspace layout (75.5 MB total):
  short* xb = (short*)d_ws;                      // 8192*1024  x bf16
  short* wqb = xb + (size_t)8192 * 1024;         // 3072*1024  w_qkv bf16
  short* wob = wqb + (size_t)3072 * 1024;        // 1024*1024  w_out bf16
  short* qkb = wob + (size_t)1024 * 1024;        // 8192*2048  q|k bf16 (q pre-scaled)
  short* vtb = qkb + (size_t)8192 * 2048;        // 64*64*2048 v transposed
  short* att = xb;  // x is dead after GEMM1; reuse for attention output

  cast_bf16_kernel<<<dim3(8192 * 1024 / 8 / 256), 256, 0, stream>>>(
      x, xb, 8192 * 1024 / 8);
  cast_bf16_kernel<<<dim3(3072 * 1024 / 8 / 256), 256, 0, stream>>>(
      w_qkv, wqb, 3072 * 1024 / 8);
  cast_bf16_kernel<<<dim3(1024 * 1024 / 8 / 256), 256, 0, stream>>>(
      w_out, wob, 1024 * 1024 / 8);

  // QKV projection: M=8192, N=3072, K=1024
  gemm_bt<0><<<dim3(64, 24), 256, 0, stream>>>(xb, wqb, 8192, 3072, 1024, qkb,
                                               vtb, nullptr, nullptr);
  // Flash attention: flat grid, XCD-swizzled; dbuf LDS, 1 barrier/tile
  attn_kernel<<<dim3(1024), 256, 0, stream>>>(qkb, vtb, att);
  // Output projection: M=8192, N=1024, K=1024, +bias, fp32 out
  gemm_bt<1><<<dim3(64, 8), 256, 0, stream>>>(att, wob, 8192, 1024, 1024,
                                              nullptr, nullptr, b_out, out);
}

// Round 5
// 256.088 us; speedup vs baseline: 1.4146x; 1.4146x over previous
//
#include <hip/hip_runtime.h>

// Problem constants (B,T,C,H fixed by the reference).
constexpr int Bn = 4, Tn = 2048, Cn = 1024, Hn = 16, Dn = 64;

typedef __attribute__((ext_vector_type(8))) short short8;
typedef __attribute__((ext_vector_type(4))) float floatx4;
typedef __attribute__((ext_vector_type(2))) unsigned uint2v;

#define DEVFN __device__ __forceinline__

// exp(s/8) = exp2(s * log2e/8); folded into Q at GEMM1 epilogue.
constexpr float SCL = 0.18033688011112042f;

// RTNE float -> bf16 raw bits (inputs are finite; no NaN handling needed).
DEVFN unsigned f2bf_u(float f) {
  unsigned u = __builtin_bit_cast(unsigned, f);
  u += 0x7fffu + ((u >> 16) & 1u);
  return u >> 16;
}
DEVFN short f2bf(float f) { return (short)f2bf_u(f); }

DEVFN floatx4 mfma16(short8 a, short8 b, floatx4 c) {
  return __builtin_amdgcn_mfma_f32_16x16x32_bf16(a, b, c, 0, 0, 0);
}

// Async global->LDS, 16B/lane. LDS dest must be wave-uniform base + lane*16.
DEVFN void gld_lds16(const void* g, void* l) {
  __builtin_amdgcn_global_load_lds(
      (const __attribute__((address_space(1))) unsigned*)g,
      (__attribute__((address_space(3))) unsigned*)l, 16, 0, 0);
}

// ---------------------------------------------------------------- cast fp32->bf16
__global__ __launch_bounds__(256) void cast_bf16_kernel(
    const float* __restrict__ in, short* __restrict__ out, int n8) {
  int i = blockIdx.x * 256 + threadIdx.x;
  if (i >= n8) return;
  const floatx4* p = (const floatx4*)in + (size_t)i * 2;
  floatx4 a = p[0], b = p[1];
  short8 r;
  r[0] = f2bf(a[0]); r[1] = f2bf(a[1]); r[2] = f2bf(a[2]); r[3] = f2bf(a[3]);
  r[4] = f2bf(b[0]); r[5] = f2bf(b[1]); r[6] = f2bf(b[2]); r[7] = f2bf(b[3]);
  ((short8*)out)[i] = r;
}

// ---------------------------------------------------------------- GEMM  Y = A @ B^T
// MODE 0: QKV projection. Q cols [0,1024) are PRE-SCALED by log2e/8 (softmax
//         fold). Q|K -> qkb [M,2048]; V cols [2048,3072) written transposed
//         into vtb[B][H][D][T] (b64-packed: consecutive acc regs = consecutive t).
// MODE 1: output projection: fp32 out + bias.
template <int MODE>
__global__ __launch_bounds__(256, 2) void gemm_bt(
    const short* __restrict__ A, const short* __restrict__ Bw, int M, int N, int K,
    short* __restrict__ qkb, short* __restrict__ vtb,
    const float* __restrict__ bias, float* __restrict__ fout) {
  __shared__ short As[128 * 32];
  __shared__ short Bs[128 * 32];
  const int tid = threadIdx.x;
  const int lane = tid & 63, wave = tid >> 6;
  const int l15 = lane & 15, quad = lane >> 4;
  const int wr = wave >> 1, wc = wave & 1;
  const int m0 = blockIdx.x * 128, n0 = blockIdx.y * 128;

  const int srow = tid >> 2;
  const int scol = (tid & 3) * 8;
  const short* Ag = A + (size_t)(m0 + srow) * K + scol;
  const short* Bg = Bw + (size_t)(n0 + srow) * K + scol;
  short* AsW = As + tid * 8;
  short* BsW = Bs + tid * 8;

  floatx4 acc[4][4] = {};

  for (int k0 = 0; k0 < K; k0 += 32) {
    gld_lds16(Ag + k0, AsW);
    gld_lds16(Ag + (size_t)64 * K + k0, AsW + 64 * 32);
    gld_lds16(Bg + k0, BsW);
    gld_lds16(Bg + (size_t)64 * K + k0, BsW + 64 * 32);
    __syncthreads();
    short8 af[4], bf[4];
#pragma unroll
    for (int i = 0; i < 4; ++i)
      af[i] = *(const short8*)(As + (wr * 64 + i * 16 + l15) * 32 + quad * 8);
#pragma unroll
    for (int i = 0; i < 4; ++i)
      bf[i] = *(const short8*)(Bs + (wc * 64 + i * 16 + l15) * 32 + quad * 8);
#pragma unroll
    for (int mi = 0; mi < 4; ++mi)
#pragma unroll
      for (int ni = 0; ni < 4; ++ni)
        acc[mi][ni] = mfma16(af[mi], bf[ni], acc[mi][ni]);
    __syncthreads();
  }

  // Epilogue. C/D layout: col = lane&15 (n), row = quad*4 + reg (m). [m89/m91]
#pragma unroll
  for (int mi = 0; mi < 4; ++mi) {
    const int row0 = m0 + wr * 64 + mi * 16 + quad * 4;
#pragma unroll
    for (int ni = 0; ni < 4; ++ni) {
      const int col = n0 + wc * 64 + ni * 16 + l15;
      if constexpr (MODE == 0) {
        if (col < 2 * Cn) {  // wave-uniform branch (128 | 2048 alignment)
#pragma unroll
          for (int r = 0; r < 4; ++r) {
            float v = acc[mi][ni][r];
            if (col < Cn) v *= SCL;  // softmax scale folded into Q
            qkb[(size_t)(row0 + r) * (2 * Cn) + col] = f2bf(v);
          }
        } else {
          const int hc = col - 2 * Cn;
          const int hh = hc >> 6, d = hc & 63;
          const int bb = row0 >> 11, t = row0 & (Tn - 1);
          uint2v pk;
          pk[0] = f2bf_u(acc[mi][ni][0]) | (f2bf_u(acc[mi][ni][1]) << 16);
          pk[1] = f2bf_u(acc[mi][ni][2]) | (f2bf_u(acc[mi][ni][3]) << 16);
          *(uint2v*)(vtb + ((size_t)((bb * Hn + hh) * Dn + d)) * Tn + t) = pk;
        }
      } else {
#pragma unroll
        for (int r = 0; r < 4; ++r)
          fout[(size_t)(row0 + r) * N + col] = acc[mi][ni][r] + bias[col];
      }
    }
  }
}

// ---------------------------------------------------------------- flash attention
// Block = 4 waves; wave owns 32 Q rows (2 i-frags). KV tile = 64, double-
// buffered LDS via async global_load_lds, ONE barrier per tile. XOR-swizzled
// LDS layouts (16B chunk ^= row&7) applied on the stager's GLOBAL address.
// Transposed math: S^T = K.Q^T, O^T = V^T.P^T; no online max; per-lane row
// sums reduced once at the end. P round-trip through per-wave 2KB LDS is done
// PER i-frag (LDS 40KB -> 4 blocks/CU).
// Grid dim3(64,16): bh = x, qt = 15-y. Linear id = bh + 64*(15-qt) gives
//   (a) globally DESCENDING qt (long blocks dispatch first -> balanced tail),
//   (b) id%8 = bh%8 -> all blocks of one bh on one XCD (L2 keeps its K/V).
// launch_bounds(256,3): VGPR cap 170 -- (256,4) forced 64 VGPRs and spilled
// ~217 MB of scratch to HBM (R4 WRITE_SIZE smoking gun). Don't tighten it.
__global__ __launch_bounds__(256, 3) void attn_kernel(
    const short* __restrict__ qk, const short* __restrict__ vt,
    short* __restrict__ att) {
  __shared__ short Ks[2][64 * 64];
  __shared__ short Vs[2][64 * 64];
  __shared__ short Ps[4][16 * 64];  // per-wave P-frag scratch (2 KB)

  const int bh = blockIdx.x;       // 0..63
  const int qt = 15 - blockIdx.y;  // globally longest-first
  const int b = bh >> 4, h = bh & 15;
  const int tid = threadIdx.x;
  const int lane = tid & 63, wave = tid >> 6;
  const int l15 = lane & 15, quad = lane >> 4;
  const int q0w = qt * 128 + wave * 32;  // this wave's 32 Q rows

  const short* qbase = qk + (size_t)(b * Tn) * 2048 + h * 64;
  const short* kbase = qbase + 1024;
  const short* vbase = vt + (size_t)(bh * 64) * Tn;
  short* pw = Ps[wave];

  // Q^T fragments (B-operand rows [i][c]) in registers for the whole kernel.
  short8 qf[2][2];
#pragma unroll
  for (int f = 0; f < 2; ++f)
#pragma unroll
    for (int ks = 0; ks < 2; ++ks)
      qf[f][ks] = *(const short8*)(qbase + (size_t)(q0w + f * 16 + l15) * 2048 +
                                   ks * 32 + quad * 8);

  floatx4 o[2][4] = {};         // O^T accumulator [f][nd], C-layout (row=d, col=i)
  float lpart[2] = {0.f, 0.f};  // per-lane row sums (i = l15)

  const int wave_nt = ((q0w + 31) >> 6) + 1;  // tiles this wave computes
  const int block_nt = 2 * qt + 2;            // loop count (uniform per block)

  const int jr = tid >> 3;  // staging row 0..31 (+32 on 2nd pass)
  const int cl = tid & 7;   // staging LDS chunk

#define STAGE(JT, BUF)                                                       \
  {                                                                          \
    const int j0s = (JT) * 64;                                               \
    _Pragma("unroll") for (int it = 0; it < 2; ++it) {                       \
      const int row = jr + it * 32;                                          \
      const int cg = cl ^ (row & 7);                                         \
      gld_lds16(kbase + (size_t)(j0s + row) * 2048 + cg * 8,                 \
                &Ks[BUF][it * 2048 + tid * 8]);                              \
      gld_lds16(vbase + (size_t)row * Tn + j0s + cg * 8,                     \
                &Vs[BUF][it * 2048 + tid * 8]);                              \
    }                                                                        \
  }

  STAGE(0, 0)
  __syncthreads();

  for (int jt = 0; jt < block_nt; ++jt) {
    const int buf = jt & 1;
    if (jt + 1 < block_nt) STAGE(jt + 1, buf ^ 1)

    if (jt < wave_nt) {
      const int j0 = jt * 64;

      // ---- S^T = K.Q^T for both i-frags; kf in 2 batches (VGPR economy)
      floatx4 st[2][4];
#pragma unroll
      for (int f = 0; f < 2; ++f)
#pragma unroll
        for (int nj = 0; nj < 4; ++nj) st[f][nj] = floatx4{0.f, 0.f, 0.f, 0.f};
#pragma unroll
      for (int half = 0; half < 2; ++half) {
        short8 kfa[2][2];
#pragma unroll
        for (int j2 = 0; j2 < 2; ++j2)
#pragma unroll
          for (int ks = 0; ks < 2; ++ks) {
            const int cld = (ks * 4 + quad) ^ (l15 & 7);
            kfa[j2][ks] = *(const short8*)(
                &Ks[buf][((half * 2 + j2) * 16 + l15) * 64 + cld * 8]);
          }
#pragma unroll
        for (int f = 0; f < 2; ++f)
#pragma unroll
          for (int j2 = 0; j2 < 2; ++j2)
#pragma unroll
            for (int ks = 0; ks < 2; ++ks)
              st[f][half * 2 + j2] =
                  mfma16(kfa[j2][ks], qf[f][ks], st[f][half * 2 + j2]);
      }

      // ---- V^T fragments (A-operand rows [d][j]), shared by both i-frags
      short8 vf[4][2];
#pragma unroll
      for (int nd = 0; nd < 4; ++nd)
#pragma unroll
        for (int ks = 0; ks < 2; ++ks) {
          const int cld = (ks * 4 + quad) ^ (l15 & 7);
          vf[nd][ks] =
              *(const short8*)(&Vs[buf][(nd * 16 + l15) * 64 + cld * 8]);
        }

      // ---- per i-frag: exp -> P -> LDS -> PV  (2KB per-wave scratch)
#pragma unroll
      for (int f = 0; f < 2; ++f) {
        const bool need_mask = (j0 + 63 > q0w + f * 16);
        const int ig = q0w + f * 16 + l15;
#pragma unroll
        for (int nj = 0; nj < 4; ++nj) {
          float p[4];
#pragma unroll
          for (int r = 0; r < 4; ++r) {
            float e = __builtin_amdgcn_exp2f(st[f][nj][r]);
            if (need_mask) {
              const int jg = j0 + nj * 16 + quad * 4 + r;
              e = (jg > ig) ? 0.f : e;
            }
            lpart[f] += e;
            p[r] = e;
          }
          // rows j = nj*16+quad*4 .. +3 are consecutive -> one b64 write
          const int c = nj * 2 + (quad >> 1);
          const int cld = c ^ (l15 & 7);
          uint2v pk;
          pk[0] = f2bf_u(p[0]) | (f2bf_u(p[1]) << 16);
          pk[1] = f2bf_u(p[2]) | (f2bf_u(p[3]) << 16);
          *(uint2v*)(&pw[l15 * 64 + cld * 8 + (quad & 1) * 4]) = pk;
        }
        // wave-local: drain P writes (lanes lockstep; DS ops in-order)
        __asm__ volatile("s_waitcnt lgkmcnt(0)" ::: "memory");

        short8 pf[2];
#pragma unroll
        for (int ks = 0; ks < 2; ++ks) {
          const int cld = (ks * 4 + quad) ^ (l15 & 7);
          pf[ks] = *(const short8*)(&pw[l15 * 64 + cld * 8]);
        }
#pragma unroll
        for (int nd = 0; nd < 4; ++nd)
#pragma unroll
          for (int ks = 0; ks < 2; ++ks)
            o[f][nd] = mfma16(vf[nd][ks], pf[ks], o[f][nd]);
        __asm__ volatile("" ::: "memory");  // keep f=1 P writes after pf reads
      }
    }
    __syncthreads();
  }

  // ---- final row sums: i = l15 -> only 2 cross-quad shuffles per frag
  float inv[2];
#pragma unroll
  for (int f = 0; f < 2; ++f) {
    float s2 = lpart[f];
    s2 += __shfl_xor(s2, 16);
    s2 += __shfl_xor(s2, 32);
    inv[f] = 1.0f / s2;
  }

  // ---- un-transpose O via per-wave LDS (16x64 per pass), coalesced stores
#pragma unroll
  for (int f = 0; f < 2; ++f) {
#pragma unroll
    for (int nd = 0; nd < 4; ++nd) {
      const int c = nd * 2 + (quad >> 1);
      const int cld = c ^ (l15 & 7);
      uint2v pk;
      pk[0] =
          f2bf_u(o[f][nd][0] * inv[f]) | (f2bf_u(o[f][nd][1] * inv[f]) << 16);
      pk[1] =
          f2bf_u(o[f][nd][2] * inv[f]) | (f2bf_u(o[f][nd][3] * inv[f]) << 16);
      *(uint2v*)(&pw[l15 * 64 + cld * 8 + (quad & 1) * 4]) = pk;
    }
    __asm__ volatile("s_waitcnt lgkmcnt(0)" ::: "memory");
#pragma unroll
    for (int ps = 0; ps < 2; ++ps) {
      const int r16 = ps * 8 + (lane >> 3);  // 0..15
      const int cn = lane & 7;
      const int cldr = cn ^ (r16 & 7);
      const short8 val = *(const short8*)(&pw[r16 * 64 + cldr * 8]);
      *(short8*)(att + (size_t)(b * Tn + q0w + f * 16 + r16) * Cn + h * 64 +
                 cn * 8) = val;
    }
    __asm__ volatile("" ::: "memory");  // f=1 writes stay after f=0 reads
  }
#undef STAGE
}

// ---------------------------------------------------------------- launch
extern "C" void kernel_launch(void* const* d_in, const int* in_sizes, int n_in,
                              void* d_out, int out_size, void* d_ws,
                              size_t ws_size, hipStream_t stream) {
  const float* x = (const float*)d_in[0];      // [B,T,C]
  const float* w_qkv = (const float*)d_in[1];  // [3C,C]
  const float* w_out = (const float*)d_in[2];  // [C,C]
  const float* b_out = (const float*)d_in[3];  // [C]
  float* out = (float*)d_out;                  // [B,T,C] fp32

  // Workspace layout (75.5 MB total):
  short* xb = (short*)d_ws;                      // 8192*1024  x bf16
  short* wqb = xb + (size_t)8192 * 1024;         // 3072*1024  w_qkv bf16
  short* wob = wqb + (size_t)3072 * 1024;        // 1024*1024  w_out bf16
  short* qkb = wob + (size_t)1024 * 1024;        // 8192*2048  q|k bf16 (q pre-scaled)
  short* vtb = qkb + (size_t)8192 * 2048;        // 64*64*2048 v transposed
  short* att = xb;  // x is dead after GEMM1; reuse for attention output

  cast_bf16_kernel<<<dim3(8192 * 1024 / 8 / 256), 256, 0, stream>>>(
      x, xb, 8192 * 1024 / 8);
  cast_bf16_kernel<<<dim3(3072 * 1024 / 8 / 256), 256, 0, stream>>>(
      w_qkv, wqb, 3072 * 1024 / 8);
  cast_bf16_kernel<<<dim3(1024 * 1024 / 8 / 256), 256, 0, stream>>>(
      w_qkv ? w_out : w_out, wob, 1024 * 1024 / 8);

  // QKV projection: M=8192, N=3072, K=1024
  gemm_bt<0><<<dim3(64, 24), 256, 0, stream>>>(xb, wqb, 8192, 3072, 1024, qkb,
                                               vtb, nullptr, nullptr);
  // Flash attention: bh = x (XCD-affine), qt descending globally
  attn_kernel<<<dim3(64, 16), 256, 0, stream>>>(qkb, vtb, att);
  // Output projection: M=8192, N=1024, K=1024, +bias, fp32 out
  gemm_bt<1><<<dim3(64, 8), 256, 0, stream>>>(att, wob, 8192, 1024, 1024,
                                              nullptr, nullptr, b_out, out);
}

// Round 6
// 229.172 us; speedup vs baseline: 1.5807x; 1.1174x over previous
//
#include <hip/hip_runtime.h>

// Problem constants (B,T,C,H fixed by the reference).
constexpr int Bn = 4, Tn = 2048, Cn = 1024, Hn = 16, Dn = 64;

typedef __attribute__((ext_vector_type(8))) short short8;
typedef __attribute__((ext_vector_type(4))) float floatx4;
typedef __attribute__((ext_vector_type(2))) unsigned uint2v;

#define DEVFN __device__ __forceinline__

// exp(s/8) = exp2(s * log2e/8); folded into Q at GEMM1 epilogue.
constexpr float SCL = 0.18033688011112042f;

// RTNE float -> bf16 raw bits (inputs are finite; no NaN handling needed).
DEVFN unsigned f2bf_u(float f) {
  unsigned u = __builtin_bit_cast(unsigned, f);
  u += 0x7fffu + ((u >> 16) & 1u);
  return u >> 16;
}
DEVFN short f2bf(float f) { return (short)f2bf_u(f); }

DEVFN floatx4 mfma16(short8 a, short8 b, floatx4 c) {
  return __builtin_amdgcn_mfma_f32_16x16x32_bf16(a, b, c, 0, 0, 0);
}

// Async global->LDS, 16B/lane. LDS dest must be wave-uniform base + lane*16.
DEVFN void gld_lds16(const void* g, void* l) {
  __builtin_amdgcn_global_load_lds(
      (const __attribute__((address_space(1))) unsigned*)g,
      (__attribute__((address_space(3))) unsigned*)l, 16, 0, 0);
}

// ---------------------------------------------------------------- fused fp32->bf16
// One kernel casts all three inputs; destinations are contiguous in ws
// (xb | wqb | wob), so dst indexes by the global group id directly.
constexpr int G_X = 8192 * 1024 / 8;   // 1048576 groups of 8
constexpr int G_WQ = 3072 * 1024 / 8;  // 393216
constexpr int G_WO = 1024 * 1024 / 8;  // 131072
__global__ __launch_bounds__(256) void cast3_kernel(
    const float* __restrict__ x, const float* __restrict__ wq,
    const float* __restrict__ wo, short* __restrict__ dst) {
  const int i = blockIdx.x * 256 + threadIdx.x;
  const float* src;
  int rel;
  if (i < G_X) {
    src = x; rel = i;
  } else if (i < G_X + G_WQ) {
    src = wq; rel = i - G_X;
  } else {
    src = wo; rel = i - (G_X + G_WQ);
  }
  const floatx4* p = (const floatx4*)src + (size_t)rel * 2;
  floatx4 a = p[0], b = p[1];
  short8 r;
  r[0] = f2bf(a[0]); r[1] = f2bf(a[1]); r[2] = f2bf(a[2]); r[3] = f2bf(a[3]);
  r[4] = f2bf(b[0]); r[5] = f2bf(b[1]); r[6] = f2bf(b[2]); r[7] = f2bf(b[3]);
  ((short8*)dst)[i] = r;
}

// ---------------------------------------------------------------- GEMM  Y = A @ B^T
// BK=64 (16 K-iterations at K=1024; half the barriers of BK=32) with
// XOR-swizzled LDS (16B chunk ^= row&7) applied on the stager's GLOBAL
// address, so fragment b128 reads are conflict-free while the LDS side keeps
// gld_lds16's required uniform+lane*16 mapping. R5 counters: 6.3M conflict
// cycles (~10us) + 32 barrier drains were the gap to the m97 plateau.
// MODE 0: QKV projection. Q cols [0,1024) PRE-SCALED by log2e/8 (softmax
//         fold). Q|K -> qkb [M,2048]; V cols [2048,3072) written transposed
//         into vtb[B][H][D][T] (b64-packed: consecutive acc regs = consecutive t).
// MODE 1: output projection: fp32 out + bias.
template <int MODE>
__global__ __launch_bounds__(256, 2) void gemm_bt(
    const short* __restrict__ A, const short* __restrict__ Bw, int M, int N, int K,
    short* __restrict__ qkb, short* __restrict__ vtb,
    const float* __restrict__ bias, float* __restrict__ fout) {
  __shared__ short As[128 * 64];  // 16 KB, [row][chunk^(row&7)] of 8-short chunks
  __shared__ short Bs[128 * 64];
  const int tid = threadIdx.x;
  const int lane = tid & 63, wave = tid >> 6;
  const int l15 = lane & 15, quad = lane >> 4;
  const int wr = wave >> 1, wc = wave & 1;
  const int m0 = blockIdx.x * 128, n0 = blockIdx.y * 128;

  // Staging slot: thread = (row r0 = tid>>3, chunk cs = tid&7); it-pass adds
  // +32 rows (swizzle invariant: (r+32)&7 == r&7). Global chunk = cs^(r&7).
  const int r0 = tid >> 3, cs = tid & 7;
  const short* Ag = A + (size_t)(m0 + r0) * K + (cs ^ (r0 & 7)) * 8;
  const short* Bg = Bw + (size_t)(n0 + r0) * K + (cs ^ (r0 & 7)) * 8;

  floatx4 acc[4][4] = {};

  for (int k0 = 0; k0 < K; k0 += 64) {
#pragma unroll
    for (int it = 0; it < 4; ++it) {
      gld_lds16(Ag + k0 + (size_t)(it * 32) * K, As + it * 2048 + tid * 8);
      gld_lds16(Bg + k0 + (size_t)(it * 32) * K, Bs + it * 2048 + tid * 8);
    }
    __syncthreads();
#pragma unroll
    for (int ks = 0; ks < 2; ++ks) {
      short8 af[4], bf[4];
#pragma unroll
      for (int i = 0; i < 4; ++i) {
        const int row = wr * 64 + i * 16 + l15;
        af[i] = *(const short8*)(As + row * 64 +
                                 ((ks * 4 + quad) ^ (l15 & 7)) * 8);
      }
#pragma unroll
      for (int i = 0; i < 4; ++i) {
        const int row = wc * 64 + i * 16 + l15;
        bf[i] = *(const short8*)(Bs + row * 64 +
                                 ((ks * 4 + quad) ^ (l15 & 7)) * 8);
      }
#pragma unroll
      for (int mi = 0; mi < 4; ++mi)
#pragma unroll
        for (int ni = 0; ni < 4; ++ni)
          acc[mi][ni] = mfma16(af[mi], bf[ni], acc[mi][ni]);
    }
    __syncthreads();
  }

  // Epilogue. C/D layout: col = lane&15 (n), row = quad*4 + reg (m). [m89/m91]
#pragma unroll
  for (int mi = 0; mi < 4; ++mi) {
    const int row0 = m0 + wr * 64 + mi * 16 + quad * 4;
#pragma unroll
    for (int ni = 0; ni < 4; ++ni) {
      const int col = n0 + wc * 64 + ni * 16 + l15;
      if constexpr (MODE == 0) {
        if (col < 2 * Cn) {  // wave-uniform branch (128 | 2048 alignment)
#pragma unroll
          for (int r = 0; r < 4; ++r) {
            float v = acc[mi][ni][r];
            if (col < Cn) v *= SCL;  // softmax scale folded into Q
            qkb[(size_t)(row0 + r) * (2 * Cn) + col] = f2bf(v);
          }
        } else {
          const int hc = col - 2 * Cn;
          const int hh = hc >> 6, d = hc & 63;
          const int bb = row0 >> 11, t = row0 & (Tn - 1);
          uint2v pk;
          pk[0] = f2bf_u(acc[mi][ni][0]) | (f2bf_u(acc[mi][ni][1]) << 16);
          pk[1] = f2bf_u(acc[mi][ni][2]) | (f2bf_u(acc[mi][ni][3]) << 16);
          *(uint2v*)(vtb + ((size_t)((bb * Hn + hh) * Dn + d)) * Tn + t) = pk;
        }
      } else {
#pragma unroll
        for (int r = 0; r < 4; ++r)
          fout[(size_t)(row0 + r) * N + col] = acc[mi][ni][r] + bias[col];
      }
    }
  }
}

// ---------------------------------------------------------------- flash attention
// Block = 4 waves; wave owns 32 Q rows (2 i-frags). KV tile = 64, double-
// buffered LDS via async global_load_lds, ONE barrier per tile. XOR-swizzled
// LDS layouts (16B chunk ^= row&7) applied on the stager's GLOBAL address.
// Transposed math: S^T = K.Q^T, O^T = V^T.P^T; no online max; per-lane row
// sums reduced once at the end. P round-trip through per-wave 2KB LDS is done
// PER i-frag (LDS 40KB -> 4 blocks/CU).
// Grid dim3(64,16): bh = x, qt = 15-y. Linear id = bh + 64*(15-qt) gives
//   (a) globally DESCENDING qt (long blocks dispatch first -> balanced tail),
//   (b) id%8 = bh%8 -> all blocks of one bh on one XCD (L2 keeps its K/V).
// launch_bounds(256,3): VGPR cap 170 -- (256,4) forced 64 VGPRs and spilled
// ~217 MB of scratch to HBM (R4 WRITE_SIZE smoking gun). Don't tighten it.
__global__ __launch_bounds__(256, 3) void attn_kernel(
    const short* __restrict__ qk, const short* __restrict__ vt,
    short* __restrict__ att) {
  __shared__ short Ks[2][64 * 64];
  __shared__ short Vs[2][64 * 64];
  __shared__ short Ps[4][16 * 64];  // per-wave P-frag scratch (2 KB)

  const int bh = blockIdx.x;       // 0..63
  const int qt = 15 - blockIdx.y;  // globally longest-first
  const int b = bh >> 4, h = bh & 15;
  const int tid = threadIdx.x;
  const int lane = tid & 63, wave = tid >> 6;
  const int l15 = lane & 15, quad = lane >> 4;
  const int q0w = qt * 128 + wave * 32;  // this wave's 32 Q rows

  const short* qbase = qk + (size_t)(b * Tn) * 2048 + h * 64;
  const short* kbase = qbase + 1024;
  const short* vbase = vt + (size_t)(bh * 64) * Tn;
  short* pw = Ps[wave];

  // Q^T fragments (B-operand rows [i][c]) in registers for the whole kernel.
  short8 qf[2][2];
#pragma unroll
  for (int f = 0; f < 2; ++f)
#pragma unroll
    for (int ks = 0; ks < 2; ++ks)
      qf[f][ks] = *(const short8*)(qbase + (size_t)(q0w + f * 16 + l15) * 2048 +
                                   ks * 32 + quad * 8);

  floatx4 o[2][4] = {};         // O^T accumulator [f][nd], C-layout (row=d, col=i)
  float lpart[2] = {0.f, 0.f};  // per-lane row sums (i = l15)

  const int wave_nt = ((q0w + 31) >> 6) + 1;  // tiles this wave computes
  const int block_nt = 2 * qt + 2;            // loop count (uniform per block)

  const int jr = tid >> 3;  // staging row 0..31 (+32 on 2nd pass)
  const int cl = tid & 7;   // staging LDS chunk

#define STAGE(JT, BUF)                                                       \
  {                                                                          \
    const int j0s = (JT) * 64;                                               \
    _Pragma("unroll") for (int it = 0; it < 2; ++it) {                       \
      const int row = jr + it * 32;                                          \
      const int cg = cl ^ (row & 7);                                         \
      gld_lds16(kbase + (size_t)(j0s + row) * 2048 + cg * 8,                 \
                &Ks[BUF][it * 2048 + tid * 8]);                              \
      gld_lds16(vbase + (size_t)row * Tn + j0s + cg * 8,                     \
                &Vs[BUF][it * 2048 + tid * 8]);                              \
    }                                                                        \
  }

  STAGE(0, 0)
  __syncthreads();

  for (int jt = 0; jt < block_nt; ++jt) {
    const int buf = jt & 1;
    if (jt + 1 < block_nt) STAGE(jt + 1, buf ^ 1)

    if (jt < wave_nt) {
      const int j0 = jt * 64;

      // ---- S^T = K.Q^T for both i-frags; kf in 2 batches (VGPR economy)
      floatx4 st[2][4];
#pragma unroll
      for (int f = 0; f < 2; ++f)
#pragma unroll
        for (int nj = 0; nj < 4; ++nj) st[f][nj] = floatx4{0.f, 0.f, 0.f, 0.f};
#pragma unroll
      for (int half = 0; half < 2; ++half) {
        short8 kfa[2][2];
#pragma unroll
        for (int j2 = 0; j2 < 2; ++j2)
#pragma unroll
          for (int ks = 0; ks < 2; ++ks) {
            const int cld = (ks * 4 + quad) ^ (l15 & 7);
            kfa[j2][ks] = *(const short8*)(
                &Ks[buf][((half * 2 + j2) * 16 + l15) * 64 + cld * 8]);
          }
#pragma unroll
        for (int f = 0; f < 2; ++f)
#pragma unroll
          for (int j2 = 0; j2 < 2; ++j2)
#pragma unroll
            for (int ks = 0; ks < 2; ++ks)
              st[f][half * 2 + j2] =
                  mfma16(kfa[j2][ks], qf[f][ks], st[f][half * 2 + j2]);
      }

      // ---- V^T fragments (A-operand rows [d][j]), shared by both i-frags
      short8 vf[4][2];
#pragma unroll
      for (int nd = 0; nd < 4; ++nd)
#pragma unroll
        for (int ks = 0; ks < 2; ++ks) {
          const int cld = (ks * 4 + quad) ^ (l15 & 7);
          vf[nd][ks] =
              *(const short8*)(&Vs[buf][(nd * 16 + l15) * 64 + cld * 8]);
        }

      // ---- per i-frag: exp -> P -> LDS -> PV  (2KB per-wave scratch)
#pragma unroll
      for (int f = 0; f < 2; ++f) {
        const bool need_mask = (j0 + 63 > q0w + f * 16);
        const int ig = q0w + f * 16 + l15;
#pragma unroll
        for (int nj = 0; nj < 4; ++nj) {
          float p[4];
#pragma unroll
          for (int r = 0; r < 4; ++r) {
            float e = __builtin_amdgcn_exp2f(st[f][nj][r]);
            if (need_mask) {
              const int jg = j0 + nj * 16 + quad * 4 + r;
              e = (jg > ig) ? 0.f : e;
            }
            lpart[f] += e;
            p[r] = e;
          }
          // rows j = nj*16+quad*4 .. +3 are consecutive -> one b64 write
          const int c = nj * 2 + (quad >> 1);
          const int cld = c ^ (l15 & 7);
          uint2v pk;
          pk[0] = f2bf_u(p[0]) | (f2bf_u(p[1]) << 16);
          pk[1] = f2bf_u(p[2]) | (f2bf_u(p[3]) << 16);
          *(uint2v*)(&pw[l15 * 64 + cld * 8 + (quad & 1) * 4]) = pk;
        }
        // wave-local: drain P writes (lanes lockstep; DS ops in-order)
        __asm__ volatile("s_waitcnt lgkmcnt(0)" ::: "memory");

        short8 pf[2];
#pragma unroll
        for (int ks = 0; ks < 2; ++ks) {
          const int cld = (ks * 4 + quad) ^ (l15 & 7);
          pf[ks] = *(const short8*)(&pw[l15 * 64 + cld * 8]);
        }
#pragma unroll
        for (int nd = 0; nd < 4; ++nd)
#pragma unroll
          for (int ks = 0; ks < 2; ++ks)
            o[f][nd] = mfma16(vf[nd][ks], pf[ks], o[f][nd]);
        __asm__ volatile("" ::: "memory");  // keep f=1 P writes after pf reads
      }
    }
    __syncthreads();
  }

  // ---- final row sums: i = l15 -> only 2 cross-quad shuffles per frag
  float inv[2];
#pragma unroll
  for (int f = 0; f < 2; ++f) {
    float s2 = lpart[f];
    s2 += __shfl_xor(s2, 16);
    s2 += __shfl_xor(s2, 32);
    inv[f] = 1.0f / s2;
  }

  // ---- un-transpose O via per-wave LDS (16x64 per pass), coalesced stores
#pragma unroll
  for (int f = 0; f < 2; ++f) {
#pragma unroll
    for (int nd = 0; nd < 4; ++nd) {
      const int c = nd * 2 + (quad >> 1);
      const int cld = c ^ (l15 & 7);
      uint2v pk;
      pk[0] =
          f2bf_u(o[f][nd][0] * inv[f]) | (f2bf_u(o[f][nd][1] * inv[f]) << 16);
      pk[1] =
          f2bf_u(o[f][nd][2] * inv[f]) | (f2bf_u(o[f][nd][3] * inv[f]) << 16);
      *(uint2v*)(&pw[l15 * 64 + cld * 8 + (quad & 1) * 4]) = pk;
    }
    __asm__ volatile("s_waitcnt lgkmcnt(0)" ::: "memory");
#pragma unroll
    for (int ps = 0; ps < 2; ++ps) {
      const int r16 = ps * 8 + (lane >> 3);  // 0..15
      const int cn = lane & 7;
      const int cldr = cn ^ (r16 & 7);
      const short8 val = *(const short8*)(&pw[r16 * 64 + cldr * 8]);
      *(short8*)(att + (size_t)(b * Tn + q0w + f * 16 + r16) * Cn + h * 64 +
                 cn * 8) = val;
    }
    __asm__ volatile("" ::: "memory");  // f=1 writes stay after f=0 reads
  }
#undef STAGE
}

// ---------------------------------------------------------------- launch
extern "C" void kernel_launch(void* const* d_in, const int* in_sizes, int n_in,
                              void* d_out, int out_size, void* d_ws,
                              size_t ws_size, hipStream_t stream) {
  const float* x = (const float*)d_in[0];      // [B,T,C]
  const float* w_qkv = (const float*)d_in[1];  // [3C,C]
  const float* w_out = (const float*)d_in[2];  // [C,C]
  const float* b_out = (const float*)d_in[3];  // [C]
  float* out = (float*)d_out;                  // [B,T,C] fp32

  // Workspace layout (75.5 MB total):
  short* xb = (short*)d_ws;                      // 8192*1024  x bf16
  short* wqb = xb + (size_t)8192 * 1024;         // 3072*1024  w_qkv bf16
  short* wob = wqb + (size_t)3072 * 1024;        // 1024*1024  w_out bf16
  short* qkb = wob + (size_t)1024 * 1024;        // 8192*2048  q|k bf16 (q pre-scaled)
  short* vtb = qkb + (size_t)8192 * 2048;        // 64*64*2048 v transposed
  short* att = xb;  // x is dead after GEMM1; reuse for attention output

  // One fused cast: dst segments (xb|wqb|wob) are contiguous in ws.
  cast3_kernel<<<dim3((G_X + G_WQ + G_WO) / 256), 256, 0, stream>>>(
      x, w_qkv, w_out, xb);

  // QKV projection: M=8192, N=3072, K=1024
  gemm_bt<0><<<dim3(64, 24), 256, 0, stream>>>(xb, wqb, 8192, 3072, 1024, qkb,
                                               vtb, nullptr, nullptr);
  // Flash attention: bh = x (XCD-affine), qt descending globally
  attn_kernel<<<dim3(64, 16), 256, 0, stream>>>(qkb, vtb, att);
  // Output projection: M=8192, N=1024, K=1024, +bias, fp32 out
  gemm_bt<1><<<dim3(64, 8), 256, 0, stream>>>(att, wob, 8192, 1024, 1024,
                                              nullptr, nullptr, b_out, out);
}